// Round 1
// baseline (130.435 us; speedup 1.0000x reference)
//
#include <hip/hip_runtime.h>
#include <math.h>

#define T_   100
#define D_   50
#define BS_  2
#define CH_  100
#define RI_  12
#define RC_  16
#define KNN_ 3
#define NJ_  (RI_ + RC_)              // 28
#define QD_  (CH_ * NJ_)              // 2800
#define PAD_ 4                        // left pad of the clamped rows
#define RP_  112                      // padded row length (floats); max idx used = 108

// 4-float vector with 4-byte alignment: lets us do unaligned-window dwordx4 loads
typedef float float4u __attribute__((ext_vector_type(4), aligned(4)));

// ---------------------------------------------------------------------------
// Kernel 1: one block per (b, t).
//  (a) top-3 KNN + column means (unchanged logic, wave-0 butterfly argmax)
//  (b) NEW: builds clamp-padded rows in workspace:
//        xpad[b][t][p] = x[b][t][clamp(p-PAD,0,99)]   (t doubles as channel c)
//        cpad[b][t][p] = ctx3[clamp(p-PAD,0,2)]
//      so kernel 2's lo/hi taps become plain positional loads.
// ---------------------------------------------------------------------------
__global__ __launch_bounds__(128) void ctx_kernel(const float* __restrict__ x,
                                                  float* __restrict__ xpad,
                                                  float* __restrict__ cpad) {
    __shared__ float cm[T_];
    __shared__ float va[128];
    __shared__ float c3[KNN_];

    const int b = blockIdx.x / T_;
    const int t = blockIdx.x - b * T_;
    const float* xb = x + b * CH_ * T_;
    const int s = threadIdx.x;

    float key = -INFINITY;
    if (s < T_) {
        float dot = 0.f, cube = 0.f, colsum = 0.f;
        #pragma unroll 10
        for (int c = 0; c < CH_; ++c) {
            float vv = xb[c * T_ + s];   // coalesced across lanes
            float vt = xb[c * T_ + t];   // uniform -> scalar load
            dot    += vv * vt;
            cube   += vv * vv * vv;
            colsum += vv;
        }
        key = 2.f * dot - cube;
        cm[s] = colsum * (1.0f / (float)CH_);
    }
    va[threadIdx.x] = key;
    __syncthreads();

    if (threadIdx.x < 64) {              // wave 0 only
        const int l = threadIdx.x;
        const float c0v = va[l];
        const float c1v = va[l + 64];    // -inf for s >= 100
        int sel0 = -100, sel1 = -100;
        for (int k = 0; k < KNN_; ++k) {
            float v0 = (l == sel0 || l == sel1) ? -INFINITY : c0v;
            float v1 = (l + 64 == sel0 || l + 64 == sel1) ? -INFINITY : c1v;
            float bv; int bi;
            if (v1 > v0) { bv = v1; bi = l + 64; } else { bv = v0; bi = l; }
            #pragma unroll
            for (int off = 32; off > 0; off >>= 1) {
                float ov = __shfl_xor(bv, off);
                int   oi = __shfl_xor(bi, off);
                if (ov > bv || (ov == bv && oi < bi)) { bv = ov; bi = oi; }
            }
            if (l == 0) c3[k] = cm[bi];
            if (k == 0) sel0 = bi; else sel1 = bi;
        }
    }
    __syncthreads();

    // build the two padded rows for this (b, t)
    if (threadIdx.x < RP_) {
        const int p = threadIdx.x;
        const int q  = p - PAD_;
        const int qx = q < 0 ? 0 : (q > T_ - 1   ? T_ - 1   : q);
        const int qc = q < 0 ? 0 : (q > KNN_ - 1 ? KNN_ - 1 : q);
        const float* __restrict__ xrow = x + (b * CH_ + t) * T_;
        xpad[(b * CH_ + t) * RP_ + p] = xrow[qx];
        cpad[(b * CH_ + t) * RP_ + p] = c3[qc];
    }
}

// ---------------------------------------------------------------------------
// Kernel 2: one block per (b, c, j) = one contiguous 20 KB output plane.
// Unified inner/context path via the clamp-padded rows:
//   lo tap = row[PAD+bi]            (== fr[clip(bi,0,L-1)] by construction)
//   hi tap = row[PAD+bi+1]          (== fr[clip(lo+1,0,L-1)] except bi==-1,
//                                     fixed with one cndmask to r1=fr[1];
//                                     bi<=-2 is masked to 0 by coord>=-1)
// Two unaligned float4 window loads replace the sel8 chains: per-element
// extraction is a static vector-lane index. bc=clamp(base,-PAD,100) keeps
// all window loads inside the 112-float row; whenever bc!=base the whole
// item is masked (coord out of [-1,L]) or aok-false (-> r0), so values
// don't matter. Mask semantics identical to the previous verified kernel.
// ---------------------------------------------------------------------------
__global__ __launch_bounds__(256) void out_kernel(const float* __restrict__ xpad,
                                                  const float* __restrict__ cpad,
                                                  float* __restrict__ out) {
    const int j = blockIdx.x % NJ_;
    const int c = (blockIdx.x / NJ_) % CH_;
    const int b = blockIdx.x / (NJ_ * CH_);

    const bool inner = (j < RI_);
    const float jsc = inner ? ((float)j + 0.5f) * (1.0f / (float)RI_)
                            : ((float)(j - RI_) + 0.5f) * (1.0f / (float)RC_);
    const float VL = inner ? (float)T_ : (float)KNN_;   // valid: coord <= VL
    const float* __restrict__ row = (inner ? xpad : cpad) + (b * CH_ + c) * RP_;
    const float r0 = row[PAD_];          // fr[0] (anchor-invalid / aok-false value)
    const float r1 = row[PAD_ + 1];      // fr[1] (hi tap when bi == -1)
    float* __restrict__ ob = out + (size_t)((b * QD_ + c * NJ_ + j) * D_) * T_;

    for (int i4 = threadIdx.x; i4 < D_ * (T_ / 4); i4 += 256) {   // 1250 items
        const int du = i4 / (T_ / 4);
        const int s0 = (i4 - du * (T_ / 4)) * 4;

        const float g = jsc * (float)(2 * du + 1) - (float)(du + 1) * 0.5f;
        const float fg = floorf(g);
        const float fracg = g - fg;          // frac(coord); s integral
        const float omf = 1.0f - fracg;
        const int base = s0 + (int)fg;       // floor(coord) for elem i is base+i

        int bc = base < -PAD_ ? -PAD_ : (base > T_ ? T_ : base);   // [-4,100]
        const float4u vl4 = *(const float4u*)(row + PAD_ + bc);      // fr[lo(i)]
        const float4u vh4 = *(const float4u*)(row + PAD_ + bc + 1);  // fr[hi(i)]

        float res[4];
        #pragma unroll
        for (int i = 0; i < 4; ++i) {
            const int sI = s0 + i;
            const int bi = base + i;
            const float coord = (float)sI + g;
            const bool valid = (coord >= -1.0f) && (coord <= VL);
            const bool aok = (sI + du) < T_;
            float vh = vh4[i];
            if (bi == -1) vh = r1;           // hi = clip(lo+1) bottom-edge fix
            const float bl = vl4[i] * omf + vh * fracg;
            res[i] = aok ? (valid ? bl : 0.0f) : r0;
        }
        // plane address == ob + 16B * i4 (du*T_ + s0 == 4*i4): block-contiguous
        *(float4*)(ob + du * T_ + s0) = make_float4(res[0], res[1], res[2], res[3]);
    }
}

extern "C" void kernel_launch(void* const* d_in, const int* in_sizes, int n_in,
                              void* d_out, int out_size, void* d_ws, size_t ws_size,
                              hipStream_t stream) {
    const float* x = (const float*)d_in[0];
    // d_in[1] (anchors) reproduced analytically; d_in[2] (index) unused.
    float* xpad = (float*)d_ws;                          // 200*112 floats
    float* cpad = xpad + (size_t)BS_ * CH_ * RP_;        // 200*112 floats
    float* out  = (float*)d_out;

    ctx_kernel<<<BS_ * T_, 128, 0, stream>>>(x, xpad, cpad);

    const int blocks = BS_ * CH_ * NJ_;   // 5600
    out_kernel<<<blocks, 256, 0, stream>>>(xpad, cpad, out);
}

// Round 2
// 130.317 us; speedup vs baseline: 1.0009x; 1.0009x over previous
//
#include <hip/hip_runtime.h>
#include <math.h>

#define T_   100
#define D_   50
#define BS_  2
#define CH_  100
#define RI_  12
#define RC_  16
#define KNN_ 3
#define NJ_  (RI_ + RC_)              // 28
#define QD_  (CH_ * NJ_)              // 2800
#define PAD_ 4                        // left pad of the clamped rows
#define RP_  112                      // padded row length (floats); max idx used = 107

// 4-float vector with 4-byte alignment: unaligned-window dwordx4 loads
typedef float float4u __attribute__((ext_vector_type(4), aligned(4)));

// ---------------------------------------------------------------------------
// Kernel 1: one block per (b, t).
//  (a) top-3 KNN + column means (wave-0 butterfly argmax; tie -> lowest idx)
//  (b) builds DUAL clamp-padded rows in workspace so kernel 2's lo/hi taps
//      are plain positional loads at the SAME window offset:
//        lo row: L[p] = fr[clip(p-PAD, 0, L-1)]
//        hi row: H[p] = fr[clip(clip(p-PAD,0,L-1)+1, 0, L-1)]
//      (reference clip order: lo = clip(floor(coord)); hi = clip(lo+1))
// ---------------------------------------------------------------------------
__global__ __launch_bounds__(128) void ctx_kernel(const float* __restrict__ x,
                                                  float* __restrict__ xlo,
                                                  float* __restrict__ xhi,
                                                  float* __restrict__ clo,
                                                  float* __restrict__ chi) {
    __shared__ float cm[T_];
    __shared__ float va[128];
    __shared__ float c3[KNN_];

    const int b = blockIdx.x / T_;
    const int t = blockIdx.x - b * T_;
    const float* xb = x + b * CH_ * T_;
    const int s = threadIdx.x;

    float key = -INFINITY;
    if (s < T_) {
        float dot = 0.f, cube = 0.f, colsum = 0.f;
        #pragma unroll 10
        for (int c = 0; c < CH_; ++c) {
            float vv = xb[c * T_ + s];   // coalesced across lanes
            float vt = xb[c * T_ + t];   // uniform -> scalar load
            dot    += vv * vt;
            cube   += vv * vv * vv;
            colsum += vv;
        }
        key = 2.f * dot - cube;
        cm[s] = colsum * (1.0f / (float)CH_);
    }
    va[threadIdx.x] = key;
    __syncthreads();

    if (threadIdx.x < 64) {              // wave 0 only
        const int l = threadIdx.x;
        const float c0v = va[l];
        const float c1v = va[l + 64];    // -inf for s >= 100
        int sel0 = -100, sel1 = -100;
        for (int k = 0; k < KNN_; ++k) {
            float v0 = (l == sel0 || l == sel1) ? -INFINITY : c0v;
            float v1 = (l + 64 == sel0 || l + 64 == sel1) ? -INFINITY : c1v;
            float bv; int bi;
            if (v1 > v0) { bv = v1; bi = l + 64; } else { bv = v0; bi = l; }
            #pragma unroll
            for (int off = 32; off > 0; off >>= 1) {
                float ov = __shfl_xor(bv, off);
                int   oi = __shfl_xor(bi, off);
                if (ov > bv || (ov == bv && oi < bi)) { bv = ov; bi = oi; }
            }
            if (l == 0) c3[k] = cm[bi];
            if (k == 0) sel0 = bi; else sel1 = bi;
        }
    }
    __syncthreads();

    // build the four padded rows for this (b, t)
    if (threadIdx.x < RP_) {
        const int p = threadIdx.x;
        const int q   = p - PAD_;
        const int qxl = q < 0 ? 0 : (q > T_ - 1 ? T_ - 1 : q);
        const int qxh = qxl + 1 > T_ - 1 ? T_ - 1 : qxl + 1;
        const int qcl = q < 0 ? 0 : (q > KNN_ - 1 ? KNN_ - 1 : q);
        const int qch = qcl + 1 > KNN_ - 1 ? KNN_ - 1 : qcl + 1;
        const float* __restrict__ xrow = x + (b * CH_ + t) * T_;
        const size_t ro = (size_t)(b * CH_ + t) * RP_ + p;
        xlo[ro] = xrow[qxl];
        xhi[ro] = xrow[qxh];
        clo[ro] = c3[qcl];
        chi[ro] = c3[qch];
    }
}

// ---------------------------------------------------------------------------
// Kernel 2: one block per (b, c, j) = one contiguous 20 KB output plane.
// Per-du constants (frac, 1-frac, floor(g), g) precomputed once per block
// into an LDS table (j is block-uniform). Taps:
//   lo = rowL[PAD + base + i], hi = rowH[PAD + base + i]  (same offset, two
//   bases; hi-row encodes the clip(lo+1) semantics incl. the base==-1 edge).
// bc = clamp(base,-PAD,T_) keeps window loads inside the 112-float rows;
// whenever bc != base every element is masked (coord outside [-1,VL]) or
// anchor-invalid (-> r0), so window values don't matter.
// Float coord/valid compares are formula-identical to the verified kernel.
// ---------------------------------------------------------------------------
__global__ __launch_bounds__(256) void out_kernel(const float* __restrict__ xlo,
                                                  const float* __restrict__ xhi,
                                                  const float* __restrict__ clo,
                                                  const float* __restrict__ chi,
                                                  float* __restrict__ out) {
    __shared__ float4 tbl[D_];           // {frac, 1-frac, int_bits(floor g), g}

    const int j = blockIdx.x % NJ_;
    const int c = (blockIdx.x / NJ_) % CH_;
    const int b = blockIdx.x / (NJ_ * CH_);

    const bool inner = (j < RI_);
    const float jsc = inner ? ((float)j + 0.5f) * (1.0f / (float)RI_)
                            : ((float)(j - RI_) + 0.5f) * (1.0f / (float)RC_);
    const float VL = inner ? (float)T_ : (float)KNN_;   // valid: coord <= VL
    const size_t roff = (size_t)(b * CH_ + c) * RP_;
    const float* __restrict__ rowL = (inner ? xlo : clo) + roff;
    const float* __restrict__ rowH = (inner ? xhi : chi) + roff;
    const float r0 = rowL[PAD_];         // fr[0] (anchor-invalid value)
    float* __restrict__ ob = out + (size_t)((b * QD_ + c * NJ_ + j) * D_) * T_;

    if (threadIdx.x < D_) {
        const int du = threadIdx.x;
        const float g  = jsc * (float)(2 * du + 1) - (float)(du + 1) * 0.5f;
        const float fg = floorf(g);
        const float fr = g - fg;
        tbl[du] = make_float4(fr, 1.0f - fr, __int_as_float((int)fg), g);
    }
    __syncthreads();

    for (int i4 = threadIdx.x; i4 < D_ * (T_ / 4); i4 += 256) {   // 1250 items
        const int du = i4 / (T_ / 4);
        const int s0 = (i4 - du * (T_ / 4)) * 4;

        const float4 e  = tbl[du];
        const float fracg = e.x;
        const float omf   = e.y;
        const int   bof   = __float_as_int(e.z);
        const float g     = e.w;
        const int base = s0 + bof;           // floor(coord) for elem i is base+i

        int bc = base < -PAD_ ? -PAD_ : (base > T_ ? T_ : base);   // [-4,100]
        const float4u vl4 = *(const float4u*)(rowL + PAD_ + bc);   // fr[lo(i)]
        const float4u vh4 = *(const float4u*)(rowH + PAD_ + bc);   // fr[hi(i)]

        float res[4];
        #pragma unroll
        for (int i = 0; i < 4; ++i) {
            const int sI = s0 + i;
            const float coord = (float)sI + g;
            const bool valid = (coord >= -1.0f) && (coord <= VL);
            const bool aok = (sI + du) < T_;
            const float bl = vl4[i] * omf + vh4[i] * fracg;
            res[i] = aok ? (valid ? bl : 0.0f) : r0;
        }
        // plane address: du*T_ + s0 == 4*i4 (block-contiguous float4 stores)
        *(float4*)(ob + 4 * i4) = make_float4(res[0], res[1], res[2], res[3]);
    }
}

extern "C" void kernel_launch(void* const* d_in, const int* in_sizes, int n_in,
                              void* d_out, int out_size, void* d_ws, size_t ws_size,
                              hipStream_t stream) {
    const float* x = (const float*)d_in[0];
    // d_in[1] (anchors) reproduced analytically; d_in[2] (index) unused.
    const size_t rows = (size_t)BS_ * CH_ * RP_;     // 22400 floats per array
    float* xlo = (float*)d_ws;
    float* xhi = xlo + rows;
    float* clo = xhi + rows;
    float* chi = clo + rows;
    float* out = (float*)d_out;

    ctx_kernel<<<BS_ * T_, 128, 0, stream>>>(x, xlo, xhi, clo, chi);

    const int blocks = BS_ * CH_ * NJ_;   // 5600
    out_kernel<<<blocks, 256, 0, stream>>>(xlo, xhi, clo, chi, out);
}